// Round 8
// baseline (218.100 us; speedup 1.0000x reference)
//
#include <hip/hip_runtime.h>
#include <math.h>

#define N 8192
#define D 512
#define TT 64              // 8192/128 tiles per side
#define NT 2080            // TT*(TT+1)/2
#define GRID 512
#define NEG_INF_SENT (-3.0e38f)

typedef __attribute__((ext_vector_type(8))) short short8x;   // 8 bf16 in 4 VGPRs
typedef __attribute__((ext_vector_type(4))) float f32x4;

#define AS1 __attribute__((address_space(1)))
#define AS3 __attribute__((address_space(3)))
// wait until <= n vector-memory ops outstanding; leave lgkm(15)/exp(7) unconstrained
#define WAITVM(n) __builtin_amdgcn_s_waitcnt(0x0F70 | (n))

__device__ inline void lse_merge(float& m1, float& s1, float m2, float s2) {
    float M = fmaxf(m1, m2);
    s1 = s1 * __expf(m1 - M) + s2 * __expf(m2 - M);
    m1 = M;
}

__device__ inline unsigned short bf16_rne(float f) {
    union { float f; unsigned u; } c; c.f = f;
    unsigned u = c.u;
    return (unsigned short)((u + 0x7FFFu + ((u >> 16) & 1u)) >> 16);
}

// ---- fused cast + row-sumsq ---------------------------------------------------
__global__ __launch_bounds__(256) void cast_rowsq_kernel(const float* __restrict__ x,
                                                         short* __restrict__ xb,
                                                         float* __restrict__ sq) {
#pragma unroll
    for (int g = 0; g < 4; ++g) {
        int row = blockIdx.x * 16 + g * 4 + (threadIdx.x >> 6);
        int lane = threadIdx.x & 63;
        const float4* xr = (const float4*)(x + (size_t)row * D);
        float4 a = xr[lane * 2], b = xr[lane * 2 + 1];
        float v[8] = {a.x, a.y, a.z, a.w, b.x, b.y, b.z, b.w};
        float s = 0.f;
        unsigned short h[8];
#pragma unroll
        for (int e = 0; e < 8; ++e) { s += v[e] * v[e]; h[e] = bf16_rne(v[e]); }
        uint4 pk;
        pk.x = (unsigned)h[0] | ((unsigned)h[1] << 16);
        pk.y = (unsigned)h[2] | ((unsigned)h[3] << 16);
        pk.z = (unsigned)h[4] | ((unsigned)h[5] << 16);
        pk.w = (unsigned)h[6] | ((unsigned)h[7] << 16);
        ((uint4*)xb)[(size_t)row * 64 + lane] = pk;
#pragma unroll
        for (int off = 32; off > 0; off >>= 1) s += __shfl_down(s, off, 64);
        if (lane == 0) sq[row] = s;
    }
}

// ---- barrier-free MFMA pair kernel -------------------------------------------
// 128x128 tile, 4 waves (64x64 each). Each wave stages ITS OWN 8 fragments
// per K-32 chunk into private LDS (dbuf 2x8KB/wave) via global_load_lds and
// syncs ONLY with s_waitcnt vmcnt(8) -> no __syncthreads in the K-loop at all
// (the m97 barrier-drain stall is structurally removed). sq pre-staged to LDS
// so the pipeline's vmcnt accounting stays exact (epilogue is lgkm-only).
__global__ __launch_bounds__(256, 2) void pair_mfma_kernel(const short* __restrict__ xb,
                                                           const float* __restrict__ sq,
                                                           float* __restrict__ bm,
                                                           float* __restrict__ bs) {
    __shared__ __align__(16) short frag_lds[4][2][8][512];  // [wave][buf][frag][16B/lane] = 64 KB
    __shared__ float sq_lds[4][5][2][64];                   // [wave][tile][i/j][row] = 10 KB

    const int p = blockIdx.x;
    const int sp = ((p & 7) << 6) | (p >> 3);        // XCD-contiguous tile runs
    const int cnt = ((sp & 15) == 0) ? 5 : 4;        // 32 extra-tile blocks spread over XCDs
    const int t0 = sp * 4 + ((sp + 15) >> 4);

    int biA[5], bjA[5];
    {
        int bi = 0;
        while ((bi + 1) * (2 * TT - bi) / 2 <= t0) ++bi;
        int bj = bi + (t0 - bi * (2 * TT - bi + 1) / 2);
#pragma unroll
        for (int e = 0; e < 5; ++e) {
            biA[e] = bi; bjA[e] = bj;
            if (bj + 1 < TT) ++bj;
            else { ++bi; bj = bi; }
            if (bi >= TT) { bi = TT - 1; bj = TT - 1; }   // phantom-tile clamp
        }
    }

    const int tid = threadIdx.x;
    const int lane = tid & 63;
    const int w = tid >> 6;
    const int wy = w >> 1, wx = w & 1;
    const int frow = lane & 15;
    const int kq = lane >> 4;

    // per-lane global element offsets for this wave's fragments, per tile
    int aBase[5], bBase[5];
#pragma unroll
    for (int e = 0; e < 5; ++e) {
        aBase[e] = (biA[e] * 128 + wy * 64 + frow) * D + kq * 8;
        bBase[e] = (bjA[e] * 128 + wx * 64 + frow) * D + kq * 8;
    }

    // pre-stage sq slices (vmcnt drained before pipeline starts)
#pragma unroll
    for (int e = 0; e < 5; ++e) {
        float vi = sq[biA[e] * 128 + wy * 64 + lane];
        float vj = sq[bjA[e] * 128 + wx * 64 + lane];
        sq_lds[w][e][0][lane] = vi;
        sq_lds[w][e][1][lane] = vj;
    }
    WAITVM(0);

    f32x4 acc[4][4];
#pragma unroll
    for (int mi = 0; mi < 4; ++mi)
#pragma unroll
        for (int ni = 0; ni < 4; ++ni) acc[mi][ni] = (f32x4){0.f, 0.f, 0.f, 0.f};
    float m_run = NEG_INF_SENT, s_run = 0.f;

    // stage 8 fragments of (tile e, k-offset k0) into buf
    auto stage = [&](int e, int k0, int buf) {
#pragma unroll
        for (int q = 0; q < 4; ++q)
            __builtin_amdgcn_global_load_lds((const AS1 void*)(xb + aBase[e] + q * 16 * D + k0),
                                             (AS3 void*)&frag_lds[w][buf][q][0], 16, 0, 0);
#pragma unroll
        for (int q = 0; q < 4; ++q)
            __builtin_amdgcn_global_load_lds((const AS1 void*)(xb + bBase[e] + q * 16 * D + k0),
                                             (AS3 void*)&frag_lds[w][buf][4 + q][0], 16, 0, 0);
    };

    auto mfma_step = [&](int buf) {
        short8x a_frag[4], b_frag[4];
#pragma unroll
        for (int u = 0; u < 4; ++u) {
            a_frag[u] = *(const short8x*)&frag_lds[w][buf][u][lane << 3];
            b_frag[u] = *(const short8x*)&frag_lds[w][buf][4 + u][lane << 3];
        }
#pragma unroll
        for (int mi = 0; mi < 4; ++mi)
#pragma unroll
            for (int ni = 0; ni < 4; ++ni)
                acc[mi][ni] = __builtin_amdgcn_mfma_f32_16x16x32_bf16(
                    a_frag[mi], b_frag[ni], acc[mi][ni], 0, 0, 0);
    };

    stage(0, 0, 0);
    int cbuf = 0;

#pragma unroll
    for (int e = 0; e < 5; ++e) {
        if (e == 4 && cnt == 4) break;
        // steps 0..14: stage next chunk of same tile, wait for current, compute
#pragma unroll 5
        for (int s = 0; s < 15; ++s) {
            stage(e, (s + 1) * 32, cbuf ^ 1);
            WAITVM(8);
            __builtin_amdgcn_sched_barrier(0);
            mfma_step(cbuf);
            cbuf ^= 1;
        }
        // step 15: stage next tile's chunk 0 (if any), wait, compute
        if (e + 1 < cnt) {
            stage(e + 1, 0, cbuf ^ 1);
            WAITVM(8);
        } else {
            WAITVM(0);
        }
        __builtin_amdgcn_sched_barrier(0);
        mfma_step(cbuf);
        cbuf ^= 1;

        // ---- per-tile epilogue (lgkm-only: sq from LDS), fold into (m,s) ----
        {
            const bool offdiag = (biA[e] != bjA[e]);
            const int i0 = biA[e] * 128, j0 = bjA[e] * 128;
            float sqj[4];
#pragma unroll
            for (int ni = 0; ni < 4; ++ni) sqj[ni] = sq_lds[w][e][1][ni * 16 + frow];
            float mloc = NEG_INF_SENT;
#pragma unroll
            for (int mi = 0; mi < 4; ++mi) {
#pragma unroll
                for (int r = 0; r < 4; ++r) {
                    int ii = mi * 16 + kq * 4 + r;           // C/D: row=(lane>>4)*4+reg
                    float sqi = sq_lds[w][e][0][ii];
                    int i = i0 + wy * 64 + ii;
#pragma unroll
                    for (int ni = 0; ni < 4; ++ni) {
                        int j = j0 + wx * 64 + ni * 16 + frow;  // col=lane&15
                        float d2 = fmaxf(sqi + sqj[ni] - 2.f * acc[mi][ni][r], 0.f);
                        float tv = (offdiag || j > i) ? (-2.0f * d2) : NEG_INF_SENT;
                        acc[mi][ni][r] = tv;
                        mloc = fmaxf(mloc, tv);
                    }
                }
            }
            float M = fmaxf(m_run, mloc);
            float sl = 0.f;
#pragma unroll
            for (int mi = 0; mi < 4; ++mi)
#pragma unroll
                for (int ni = 0; ni < 4; ++ni) {
#pragma unroll
                    for (int r = 0; r < 4; ++r) sl += __expf(acc[mi][ni][r] - M);
                    acc[mi][ni] = (f32x4){0.f, 0.f, 0.f, 0.f};
                }
            s_run = s_run * __expf(m_run - M) + sl;
            m_run = M;
        }
    }

    // ---- block reduction (single barrier, after all pipelines) ---------------
    float m = m_run, s = s_run;
#pragma unroll
    for (int off = 32; off > 0; off >>= 1) {
        float m2 = __shfl_down(m, off, 64);
        float s2 = __shfl_down(s, off, 64);
        lse_merge(m, s, m2, s2);
    }
    __shared__ float rm[4], rs[4];
    if (lane == 0) { rm[w] = m; rs[w] = s; }
    __syncthreads();
    if (tid == 0) {
#pragma unroll
        for (int v = 1; v < 4; ++v) lse_merge(rm[0], rs[0], rm[v], rs[v]);
        bm[p] = rm[0];
        bs[p] = rs[0];
    }
}

__global__ __launch_bounds__(256) void finalize_kernel(const float* __restrict__ bm,
                                                       const float* __restrict__ bs,
                                                       int nblocks,
                                                       float* __restrict__ out) {
    const int tid = threadIdx.x;
    float m = NEG_INF_SENT, s = 0.f;
    for (int b = tid; b < nblocks; b += 256) lse_merge(m, s, bm[b], bs[b]);
#pragma unroll
    for (int off = 32; off > 0; off >>= 1) {
        float m2 = __shfl_down(m, off, 64);
        float s2 = __shfl_down(s, off, 64);
        lse_merge(m, s, m2, s2);
    }
    __shared__ float rm[4], rs[4];
    if ((tid & 63) == 0) { rm[tid >> 6] = m; rs[tid >> 6] = s; }
    __syncthreads();
    if (tid == 0) {
#pragma unroll
        for (int v = 1; v < 4; ++v) lse_merge(rm[0], rs[0], rm[v], rs[v]);
        const float log_num_pairs = 17.3285362f;  // log(8192*8191/2)
        out[0] = rm[0] + logf(rs[0]) - log_num_pairs;
    }
}

extern "C" void kernel_launch(void* const* d_in, const int* in_sizes, int n_in,
                              void* d_out, int out_size, void* d_ws, size_t ws_size,
                              hipStream_t stream) {
    const float* x = (const float*)d_in[0];
    float* out = (float*)d_out;

    const size_t xb_bytes = (size_t)N * D * sizeof(short);  // 8 MB
    short* xb = (short*)d_ws;
    float* sq = (float*)((char*)d_ws + xb_bytes);
    float* bm = sq + N;
    float* bs = bm + GRID;

    cast_rowsq_kernel<<<N / 16, 256, 0, stream>>>(x, xb, sq);
    pair_mfma_kernel<<<GRID, 256, 0, stream>>>(xb, sq, bm, bs);
    finalize_kernel<<<1, 256, 0, stream>>>(bm, bs, GRID, out);
}

// Round 9
// 204.385 us; speedup vs baseline: 1.0671x; 1.0671x over previous
//
#include <hip/hip_runtime.h>
#include <math.h>

#define N 8192
#define D 512
#define TT 64              // 8192/128 tiles per side
#define NT 2080            // TT*(TT+1)/2
#define GRID 512
#define ROWB 144           // LDS bytes per 64k-chunk row (128 data + 16 pad)
#define NEG_INF_SENT (-3.0e38f)

typedef __attribute__((ext_vector_type(8))) short short8x;   // 8 bf16 in 4 VGPRs
typedef __attribute__((ext_vector_type(4))) float f32x4;

__device__ inline void lse_merge(float& m1, float& s1, float m2, float s2) {
    float M = fmaxf(m1, m2);
    s1 = s1 * __expf(m1 - M) + s2 * __expf(m2 - M);
    m1 = M;
}

__device__ inline unsigned short bf16_rne(float f) {
    union { float f; unsigned u; } c; c.f = f;
    unsigned u = c.u;
    return (unsigned short)((u + 0x7FFFu + ((u >> 16) & 1u)) >> 16);
}

// ---- fused cast + row-sumsq ---------------------------------------------------
__global__ __launch_bounds__(256) void cast_rowsq_kernel(const float* __restrict__ x,
                                                         short* __restrict__ xb,
                                                         float* __restrict__ sq) {
#pragma unroll
    for (int g = 0; g < 4; ++g) {
        int row = blockIdx.x * 16 + g * 4 + (threadIdx.x >> 6);
        int lane = threadIdx.x & 63;
        const float4* xr = (const float4*)(x + (size_t)row * D);
        float4 a = xr[lane * 2], b = xr[lane * 2 + 1];
        float v[8] = {a.x, a.y, a.z, a.w, b.x, b.y, b.z, b.w};
        float s = 0.f;
        unsigned short h[8];
#pragma unroll
        for (int e = 0; e < 8; ++e) { s += v[e] * v[e]; h[e] = bf16_rne(v[e]); }
        uint4 pk;
        pk.x = (unsigned)h[0] | ((unsigned)h[1] << 16);
        pk.y = (unsigned)h[2] | ((unsigned)h[3] << 16);
        pk.z = (unsigned)h[4] | ((unsigned)h[5] << 16);
        pk.w = (unsigned)h[6] | ((unsigned)h[7] << 16);
        ((uint4*)xb)[(size_t)row * 64 + lane] = pk;
#pragma unroll
        for (int off = 32; off > 0; off >>= 1) s += __shfl_down(s, off, 64);
        if (lane == 0) sq[row] = s;
    }
}

// ---- persistent MFMA pair kernel, m93-style staging --------------------------
// 128x128 tile, 4 waves (64x64 wave-tile, acc[4][4]=64 AGPR), K-chunk 64,
// LDS dbuf 2x36KB (row stride 144B: ds_write & frag ds_read both 2 lanes/bank
// = free). Staging loads coalesced: each dwordx4 instr = 8 rows x 128B = 16
// cache lines (vs 64 for the r3-r8 row-strided DMA). 4-5 tiles/block streamed
// back-to-back; 2 blocks/CU resident (LDS 72KB, regs ~170 <= 256 @ 2 w/SIMD).
__global__ __launch_bounds__(256, 2) void pair_mfma_kernel(const short* __restrict__ xb,
                                                           const float* __restrict__ sq,
                                                           float* __restrict__ bm,
                                                           float* __restrict__ bs) {
    __shared__ __align__(16) char AB_lds[2][2][128 * ROWB];  // [buf][A|B] = 73728 B

    const int p = blockIdx.x;
    const int sp = ((p & 7) << 6) | (p >> 3);        // XCD-contiguous tile runs
    const int cnt = ((sp & 15) == 0) ? 5 : 4;        // 32 extra-tile blocks, XCD-spread
    const int t0 = sp * 4 + ((sp + 15) >> 4);

    int bi = 0;
    while ((bi + 1) * (2 * TT - bi) / 2 <= t0) ++bi;
    int bj = bi + (t0 - bi * (2 * TT - bi + 1) / 2);

    const int tid = threadIdx.x;
    const int lane = tid & 63;
    const int w = tid >> 6;
    const int wy = w >> 1, wx = w & 1;
    const int frow = lane & 15;
    const int kq = lane >> 4;

    // staging maps: thread covers rows {srow+32j}, 16B unit `sunit` of the 128B chunk-row
    const int srow = tid >> 3;          // 0..31
    const int sunit = tid & 7;          // 0..7
    const int lOff = srow * ROWB + sunit * 16;       // + j*32*ROWB
    const char* xbB = (const char*)xb;

    size_t gA = (size_t)(bi * 128 + srow) * 1024 + sunit * 16;
    size_t gB = (size_t)(bj * 128 + srow) * 1024 + sunit * 16;

    uint4 rA[4], rB[4];

    f32x4 acc[4][4];
#pragma unroll
    for (int mi = 0; mi < 4; ++mi)
#pragma unroll
        for (int ni = 0; ni < 4; ++ni) acc[mi][ni] = (f32x4){0.f, 0.f, 0.f, 0.f};
    float m_run = NEG_INF_SENT, s_run = 0.f;

    // prologue: chunk 0 -> buf 0
#pragma unroll
    for (int j = 0; j < 4; ++j) {
        rA[j] = *(const uint4*)(xbB + gA + j * 32768);
        rB[j] = *(const uint4*)(xbB + gB + j * 32768);
    }
#pragma unroll
    for (int j = 0; j < 4; ++j) {
        *(uint4*)(AB_lds[0][0] + lOff + j * (32 * ROWB)) = rA[j];
        *(uint4*)(AB_lds[0][1] + lOff + j * (32 * ROWB)) = rB[j];
    }
    __syncthreads();

    for (int e = 0; e < cnt; ++e) {
        int nbi = (bj + 1 < TT) ? bi : bi + 1;
        int nbj = (bj + 1 < TT) ? bj + 1 : bi + 1;
        if (nbi >= TT) { nbi = TT - 1; nbj = TT - 1; }   // phantom clamp (never computed)
        const size_t gA_n = (size_t)(nbi * 128 + srow) * 1024 + sunit * 16;
        const size_t gB_n = (size_t)(nbj * 128 + srow) * 1024 + sunit * 16;
        const bool more = (e + 1 < cnt);

#pragma unroll
        for (int c = 0; c < 8; ++c) {
            const int cur = c & 1, nxt = cur ^ 1;
            const bool have_next = (c < 7) || more;
            // 1. issue next chunk's global loads (consumed after this step's MFMA)
            if (have_next) {
                const size_t a0 = (c < 7) ? gA + (c + 1) * 128 : gA_n;
                const size_t b0 = (c < 7) ? gB + (c + 1) * 128 : gB_n;
#pragma unroll
                for (int j = 0; j < 4; ++j) {
                    rA[j] = *(const uint4*)(xbB + a0 + j * 32768);
                    rB[j] = *(const uint4*)(xbB + b0 + j * 32768);
                }
            }
            // 2. compute current chunk from LDS
#pragma unroll
            for (int ks = 0; ks < 2; ++ks) {
                short8x af[4], bf[4];
#pragma unroll
                for (int u = 0; u < 4; ++u) {
                    af[u] = *(const short8x*)(AB_lds[cur][0] + (wy * 64 + u * 16 + frow) * ROWB + ks * 64 + kq * 16);
                    bf[u] = *(const short8x*)(AB_lds[cur][1] + (wx * 64 + u * 16 + frow) * ROWB + ks * 64 + kq * 16);
                }
#pragma unroll
                for (int mi = 0; mi < 4; ++mi)
#pragma unroll
                    for (int ni = 0; ni < 4; ++ni)
                        acc[mi][ni] = __builtin_amdgcn_mfma_f32_16x16x32_bf16(
                            af[mi], bf[ni], acc[mi][ni], 0, 0, 0);
            }
            // 3. write next chunk to the other buffer (vmcnt wait covered by MFMA)
            if (have_next) {
#pragma unroll
                for (int j = 0; j < 4; ++j) {
                    *(uint4*)(AB_lds[nxt][0] + lOff + j * (32 * ROWB)) = rA[j];
                    *(uint4*)(AB_lds[nxt][1] + lOff + j * (32 * ROWB)) = rB[j];
                }
            }
            // 4. per-tile epilogue on last chunk: fold t=-2*d2 into running (m,s)
            if (c == 7) {
                const bool offdiag = (bi != bj);
                const int i0 = bi * 128, j0 = bj * 128;
                float sqj[4];
#pragma unroll
                for (int ni = 0; ni < 4; ++ni) sqj[ni] = sq[j0 + wx * 64 + ni * 16 + frow];
                float mloc = NEG_INF_SENT;
#pragma unroll
                for (int mi = 0; mi < 4; ++mi) {
#pragma unroll
                    for (int r = 0; r < 4; ++r) {
                        int i = i0 + wy * 64 + mi * 16 + kq * 4 + r;   // C/D: row=(lane>>4)*4+reg
                        float sqi = sq[i];
#pragma unroll
                        for (int ni = 0; ni < 4; ++ni) {
                            int j = j0 + wx * 64 + ni * 16 + frow;     // col=lane&15
                            float d2 = fmaxf(sqi + sqj[ni] - 2.f * acc[mi][ni][r], 0.f);
                            float tv = (offdiag || j > i) ? (-2.0f * d2) : NEG_INF_SENT;
                            acc[mi][ni][r] = tv;
                            mloc = fmaxf(mloc, tv);
                        }
                    }
                }
                float M = fmaxf(m_run, mloc);
                float sl = 0.f;
#pragma unroll
                for (int mi = 0; mi < 4; ++mi)
#pragma unroll
                    for (int ni = 0; ni < 4; ++ni) {
#pragma unroll
                        for (int r = 0; r < 4; ++r) sl += __expf(acc[mi][ni][r] - M);
                        acc[mi][ni] = (f32x4){0.f, 0.f, 0.f, 0.f};
                    }
                s_run = s_run * __expf(m_run - M) + sl;
                m_run = M;
            }
            __syncthreads();
        }
        bi = nbi; bj = nbj; gA = gA_n; gB = gB_n;
    }

    // ---- block reduction -----------------------------------------------------
    float m = m_run, s = s_run;
#pragma unroll
    for (int off = 32; off > 0; off >>= 1) {
        float m2 = __shfl_down(m, off, 64);
        float s2 = __shfl_down(s, off, 64);
        lse_merge(m, s, m2, s2);
    }
    __shared__ float rm[4], rs[4];
    if (lane == 0) { rm[w] = m; rs[w] = s; }
    __syncthreads();
    if (tid == 0) {
#pragma unroll
        for (int v = 1; v < 4; ++v) lse_merge(rm[0], rs[0], rm[v], rs[v]);
        bm[p] = rm[0];
        bs[p] = rs[0];
    }
}

__global__ __launch_bounds__(256) void finalize_kernel(const float* __restrict__ bm,
                                                       const float* __restrict__ bs,
                                                       int nblocks,
                                                       float* __restrict__ out) {
    const int tid = threadIdx.x;
    float m = NEG_INF_SENT, s = 0.f;
    for (int b = tid; b < nblocks; b += 256) lse_merge(m, s, bm[b], bs[b]);
#pragma unroll
    for (int off = 32; off > 0; off >>= 1) {
        float m2 = __shfl_down(m, off, 64);
        float s2 = __shfl_down(s, off, 64);
        lse_merge(m, s, m2, s2);
    }
    __shared__ float rm[4], rs[4];
    if ((tid & 63) == 0) { rm[tid >> 6] = m; rs[tid >> 6] = s; }
    __syncthreads();
    if (tid == 0) {
#pragma unroll
        for (int v = 1; v < 4; ++v) lse_merge(rm[0], rs[0], rm[v], rs[v]);
        const float log_num_pairs = 17.3285362f;  // log(8192*8191/2)
        out[0] = rm[0] + logf(rs[0]) - log_num_pairs;
    }
}

extern "C" void kernel_launch(void* const* d_in, const int* in_sizes, int n_in,
                              void* d_out, int out_size, void* d_ws, size_t ws_size,
                              hipStream_t stream) {
    const float* x = (const float*)d_in[0];
    float* out = (float*)d_out;

    const size_t xb_bytes = (size_t)N * D * sizeof(short);  // 8 MB
    short* xb = (short*)d_ws;
    float* sq = (float*)((char*)d_ws + xb_bytes);
    float* bm = sq + N;
    float* bs = bm + GRID;

    cast_rowsq_kernel<<<N / 16, 256, 0, stream>>>(x, xb, sq);
    pair_mfma_kernel<<<GRID, 256, 0, stream>>>(xb, sq, bm, bs);
    finalize_kernel<<<1, 256, 0, stream>>>(bm, bs, GRID, out);
}

// Round 10
// 113.707 us; speedup vs baseline: 1.9181x; 1.7975x over previous
//
#include <hip/hip_runtime.h>
#include <hip/hip_fp8.h>
#include <math.h>

#define N 8192
#define D 512
#define NEG_INF_SENT (-3.0e38f)
#define SCALE1 0x7F7F7F7F   // E8M0 = 127 -> 2^0 = 1.0 in all four bytes

typedef __attribute__((ext_vector_type(8))) int int8x;      // 32 fp8 in 8 VGPRs
typedef __attribute__((ext_vector_type(16))) float f32x16;  // 32x32 C/D frag

#define AS1 __attribute__((address_space(1)))
#define AS3 __attribute__((address_space(3)))

__device__ inline void lse_merge(float& m1, float& s1, float m2, float s2) {
    float M = fmaxf(m1, m2);
    s1 = s1 * __expf(m1 - M) + s2 * __expf(m2 - M);
    m1 = M;
}

// ---- fused cast(fp32->fp8 e4m3) + row-sumsq ----------------------------------
__global__ __launch_bounds__(256) void cast_rowsq_kernel(const float* __restrict__ x,
                                                         unsigned char* __restrict__ xb,
                                                         float* __restrict__ sq) {
#pragma unroll
    for (int g = 0; g < 4; ++g) {
        int row = blockIdx.x * 16 + g * 4 + (threadIdx.x >> 6);
        int lane = threadIdx.x & 63;
        const float4* xr = (const float4*)(x + (size_t)row * D);
        float4 a = xr[lane * 2], b = xr[lane * 2 + 1];
        float v[8] = {a.x, a.y, a.z, a.w, b.x, b.y, b.z, b.w};
        float s = 0.f;
        unsigned int byt[8];
#pragma unroll
        for (int e = 0; e < 8; ++e) {
            s += v[e] * v[e];
            __hip_fp8_e4m3 f8(v[e]);            // OCP e4m3fn
            byt[e] = (unsigned int)f8.__x;
        }
        uint2 pk;
        pk.x = byt[0] | (byt[1] << 8) | (byt[2] << 16) | (byt[3] << 24);
        pk.y = byt[4] | (byt[5] << 8) | (byt[6] << 16) | (byt[7] << 24);
        ((uint2*)xb)[(size_t)row * 64 + lane] = pk;
#pragma unroll
        for (int off = 32; off > 0; off >>= 1) s += __shfl_down(s, off, 64);
        if (lane == 0) sq[row] = s;
    }
}

// ---- MX-fp8 MFMA pair kernel: r5 skeleton at 2x rate -------------------------
// 256x256 tile, 8 waves (wave-tile 64x128 = 2x4 frags of 32x32), K-chunk 64,
// LDS dbuf 2x32KB, global_load_lds staging in fragment order (lane l supplies
// row l&31, k-half l>>5 of its frag; 2 DMAs of 16B per 32B lane-fragment, read
// back at the same lane*16 offsets). mfma_scale_f32_32x32x64_f8f6f4 with unit
// E8M0 scales. C/D layout (verified m74/m101): col=lane&31,
// row=(reg&3)+8*(reg>>2)+4*(lane>>5).
__global__ __launch_bounds__(512, 2) void pair_mfma_kernel(const unsigned char* __restrict__ xb,
                                                           const float* __restrict__ sq,
                                                           float* __restrict__ bm,
                                                           float* __restrict__ bs) {
    __shared__ __align__(16) unsigned char lds[2][16][2048];  // [buf][frag 0-7 A, 8-15 B] = 64 KB

    const int T = N / 256;  // 32
    const int b = (blockIdx.x & 7) * 66 + (blockIdx.x >> 3);  // XCD-contiguous runs (528 = 8*66)
    int bi = 0;
    while ((bi + 1) * (2 * T - bi) / 2 <= b) ++bi;
    const int bj = bi + (b - bi * (2 * T - bi + 1) / 2);
    const int i0 = bi * 256, j0 = bj * 256;

    const int tid = threadIdx.x;
    const int lane = tid & 63;
    const int w = tid >> 6;          // 0..7
    const int wy = w >> 1;           // 0..3: i 64-chunk
    const int wx = w & 1;            // 0..1: j 128-chunk
    const int l31 = lane & 31;
    const int l5 = lane >> 5;
    const int f0 = w << 1;           // this wave stages frags f0, f0+1

    int rowoff[2];
#pragma unroll
    for (int q = 0; q < 2; ++q) {
        int f = f0 + q;
        int base = (f < 8) ? (i0 + f * 32) : (j0 + (f - 8) * 32);
        rowoff[q] = (base + l31) * D + l5 * 32;
    }

    f32x16 acc[2][4];
#pragma unroll
    for (int mi = 0; mi < 2; ++mi)
#pragma unroll
        for (int ni = 0; ni < 4; ++ni)
#pragma unroll
            for (int r = 0; r < 16; ++r) acc[mi][ni][r] = 0.f;

    // stage one K-64 chunk: 2 frags/wave x 2 halves, 16B per lane each
    auto stage = [&](int c, int buf) {
#pragma unroll
        for (int q = 0; q < 2; ++q)
#pragma unroll
            for (int h = 0; h < 2; ++h)
                __builtin_amdgcn_global_load_lds(
                    (const AS1 void*)(xb + rowoff[q] + c * 64 + h * 16),
                    (AS3 void*)&lds[buf][f0 + q][h << 10], 16, 0, 0);
    };

    stage(0, 0);
    __syncthreads();

    for (int c = 0; c < 8; ++c) {
        const int cur = c & 1;
        if (c < 7) stage(c + 1, cur ^ 1);
        int8x af[2], bf[4];
#pragma unroll
        for (int mi = 0; mi < 2; ++mi) {
            uint4 lo = *(const uint4*)&lds[cur][wy * 2 + mi][lane << 4];
            uint4 hi = *(const uint4*)&lds[cur][wy * 2 + mi][1024 + (lane << 4)];
            af[mi][0] = lo.x; af[mi][1] = lo.y; af[mi][2] = lo.z; af[mi][3] = lo.w;
            af[mi][4] = hi.x; af[mi][5] = hi.y; af[mi][6] = hi.z; af[mi][7] = hi.w;
        }
#pragma unroll
        for (int ni = 0; ni < 4; ++ni) {
            uint4 lo = *(const uint4*)&lds[cur][8 + wx * 4 + ni][lane << 4];
            uint4 hi = *(const uint4*)&lds[cur][8 + wx * 4 + ni][1024 + (lane << 4)];
            bf[ni][0] = lo.x; bf[ni][1] = lo.y; bf[ni][2] = lo.z; bf[ni][3] = lo.w;
            bf[ni][4] = hi.x; bf[ni][5] = hi.y; bf[ni][6] = hi.z; bf[ni][7] = hi.w;
        }
#pragma unroll
        for (int mi = 0; mi < 2; ++mi)
#pragma unroll
            for (int ni = 0; ni < 4; ++ni)
                acc[mi][ni] = __builtin_amdgcn_mfma_scale_f32_32x32x64_f8f6f4(
                    af[mi], bf[ni], acc[mi][ni], 0, 0, 0, SCALE1, 0, SCALE1);
        __syncthreads();
    }

    // ---- branch-free epilogue ------------------------------------------------
    const bool offdiag = (bi != bj);
    float sqj[4];
#pragma unroll
    for (int ni = 0; ni < 4; ++ni) sqj[ni] = sq[j0 + wx * 128 + ni * 32 + l31];

    float m = NEG_INF_SENT;
#pragma unroll
    for (int mi = 0; mi < 2; ++mi) {
#pragma unroll
        for (int r = 0; r < 16; ++r) {
            int row32 = (r & 3) + 8 * (r >> 2) + 4 * l5;
            int i = i0 + wy * 64 + mi * 32 + row32;
            float sqi = sq[i];
#pragma unroll
            for (int ni = 0; ni < 4; ++ni) {
                int j = j0 + wx * 128 + ni * 32 + l31;
                float d2 = fmaxf(sqi + sqj[ni] - 2.f * acc[mi][ni][r], 0.f);
                float tv = (offdiag || j > i) ? (-2.0f * d2) : NEG_INF_SENT;
                acc[mi][ni][r] = tv;
                m = fmaxf(m, tv);
            }
        }
    }
    float s = 0.f;
#pragma unroll
    for (int mi = 0; mi < 2; ++mi)
#pragma unroll
        for (int ni = 0; ni < 4; ++ni)
#pragma unroll
            for (int r = 0; r < 16; ++r)
                s += __expf(acc[mi][ni][r] - m);

#pragma unroll
    for (int off = 32; off > 0; off >>= 1) {
        float m2 = __shfl_down(m, off, 64);
        float s2 = __shfl_down(s, off, 64);
        lse_merge(m, s, m2, s2);
    }
    __shared__ float rm[8], rs[8];
    if (lane == 0) { rm[w] = m; rs[w] = s; }
    __syncthreads();
    if (tid == 0) {
#pragma unroll
        for (int v = 1; v < 8; ++v) lse_merge(rm[0], rs[0], rm[v], rs[v]);
        bm[b] = rm[0];
        bs[b] = rs[0];
    }
}

__global__ __launch_bounds__(256) void finalize_kernel(const float* __restrict__ bm,
                                                       const float* __restrict__ bs,
                                                       int nblocks,
                                                       float* __restrict__ out) {
    const int tid = threadIdx.x;
    float m = NEG_INF_SENT, s = 0.f;
    for (int b = tid; b < nblocks; b += 256) lse_merge(m, s, bm[b], bs[b]);
#pragma unroll
    for (int off = 32; off > 0; off >>= 1) {
        float m2 = __shfl_down(m, off, 64);
        float s2 = __shfl_down(s, off, 64);
        lse_merge(m, s, m2, s2);
    }
    __shared__ float rm[4], rs[4];
    if ((tid & 63) == 0) { rm[tid >> 6] = m; rs[tid >> 6] = s; }
    __syncthreads();
    if (tid == 0) {
#pragma unroll
        for (int v = 1; v < 4; ++v) lse_merge(rm[0], rs[0], rm[v], rs[v]);
        const float log_num_pairs = 17.3285362f;  // log(8192*8191/2)
        out[0] = rm[0] + logf(rs[0]) - log_num_pairs;
    }
}

extern "C" void kernel_launch(void* const* d_in, const int* in_sizes, int n_in,
                              void* d_out, int out_size, void* d_ws, size_t ws_size,
                              hipStream_t stream) {
    const float* x = (const float*)d_in[0];
    float* out = (float*)d_out;

    const int T = N / 256;                    // 32
    const int nb = T * (T + 1) / 2;           // 528
    const size_t xb_bytes = (size_t)N * D;    // 4 MB fp8

    unsigned char* xb = (unsigned char*)d_ws;
    float* sq = (float*)((char*)d_ws + xb_bytes);
    float* bm = sq + N;
    float* bs = bm + nb;

    cast_rowsq_kernel<<<N / 16, 256, 0, stream>>>(x, xb, sq);
    pair_mfma_kernel<<<nb, 512, 0, stream>>>(xb, sq, bm, bs);
    finalize_kernel<<<1, 256, 0, stream>>>(bm, bs, nb, out);
}

// Round 11
// 99.186 us; speedup vs baseline: 2.1989x; 1.1464x over previous
//
#include <hip/hip_runtime.h>
#include <hip/hip_fp8.h>
#include <math.h>

#define N 8192
#define D 512
#define NEG_INF_SENT (-3.0e38f)
#define SCALE1 0x7F7F7F7F   // E8M0 = 127 -> 2^0 = 1.0 in all four bytes

typedef __attribute__((ext_vector_type(8))) int int8x;      // 32 fp8 in 8 VGPRs
typedef __attribute__((ext_vector_type(16))) float f32x16;  // 32x32 C/D frag

#define AS1 __attribute__((address_space(1)))
#define AS3 __attribute__((address_space(3)))

__device__ inline void lse_merge(float& m1, float& s1, float m2, float s2) {
    float M = fmaxf(m1, m2);
    s1 = s1 * __expf(m1 - M) + s2 * __expf(m2 - M);
    m1 = M;
}

// ---- fused cast(fp32->fp8 e4m3, FRAGMENT-SWIZZLED layout) + row-sumsq --------
// xb layout: for 32-row group g, K-chunk c (64 k), half h (16-B k-seg):
//   unit16 at ((g*8+c)*2+h)*1024 + ((kseg32)*32 + row&31)*16
// so a (frag,h) = 1 KB is CONTIGUOUS and equals the exact lane-order image the
// MFMA operand wants (lane l: row l&31, k=(l>>5)*32 + h*16 + [0,16)).
__global__ __launch_bounds__(256) void cast_rowsq_kernel(const float* __restrict__ x,
                                                         unsigned char* __restrict__ xb,
                                                         float* __restrict__ sq) {
#pragma unroll
    for (int g4 = 0; g4 < 4; ++g4) {
        int row = blockIdx.x * 16 + g4 * 4 + (threadIdx.x >> 6);
        int lane = threadIdx.x & 63;
        const float4* xr = (const float4*)(x + (size_t)row * D);
        float4 a = xr[lane * 2], b = xr[lane * 2 + 1];
        float v[8] = {a.x, a.y, a.z, a.w, b.x, b.y, b.z, b.w};
        float s = 0.f;
        unsigned int byt[8];
#pragma unroll
        for (int e = 0; e < 8; ++e) {
            s += v[e] * v[e];
            __hip_fp8_e4m3 f8(v[e]);            // OCP e4m3fn
            byt[e] = (unsigned int)f8.__x;
        }
        uint2 pk;
        pk.x = byt[0] | (byt[1] << 8) | (byt[2] << 16) | (byt[3] << 24);
        pk.y = byt[4] | (byt[5] << 8) | (byt[6] << 16) | (byt[7] << 24);
        // this lane's 8 elems are k = lane*8 .. lane*8+7 of `row`
        int g = row >> 5, rl = row & 31;
        int c = lane >> 3;                 // K-chunk
        int l5 = (lane >> 2) & 1;          // 32-k segment within chunk
        int h = (lane >> 1) & 1;           // 16-B half within segment
        int bb = (lane & 1) << 3;          // byte within 16-B unit
        size_t addr = ((size_t)((g * 8 + c) * 2 + h) << 10) + ((l5 * 32 + rl) << 4) + bb;
        *(uint2*)(xb + addr) = pk;
#pragma unroll
        for (int off = 32; off > 0; off >>= 1) s += __shfl_down(s, off, 64);
        if (lane == 0) sq[row] = s;
    }
}

// ---- MX-fp8 MFMA pair kernel (r10 skeleton, dense swizzled staging) ----------
// 256x256 tile, 8 waves (wave-tile 64x128 = 2x4 frags of 32x32x64), K-chunk 64,
// LDS dbuf 2x32KB. Staging: 4 DMAs/wave, each a CONTIGUOUS 1KB (16 cache lines,
// wave-uniform base -> zero per-lane addressing). LDS image identical to r10
// (lane*16 reads, measured conflict-free). C/D layout (m74/m101): col=lane&31,
// row=(reg&3)+8*(reg>>2)+4*(lane>>5).
__global__ __launch_bounds__(512, 2) void pair_mfma_kernel(const unsigned char* __restrict__ xb,
                                                           const float* __restrict__ sq,
                                                           float* __restrict__ bm,
                                                           float* __restrict__ bs) {
    __shared__ __align__(16) unsigned char lds[2][16][2048];  // [buf][frag 0-7 A, 8-15 B] = 64 KB

    const int T = N / 256;  // 32
    const int b = (blockIdx.x & 7) * 66 + (blockIdx.x >> 3);  // XCD-contiguous runs (528 = 8*66)
    int bi = 0;
    while ((bi + 1) * (2 * T - bi) / 2 <= b) ++bi;
    const int bj = bi + (b - bi * (2 * T - bi + 1) / 2);
    const int i0 = bi * 256, j0 = bj * 256;

    const int tid = threadIdx.x;
    const int lane = tid & 63;
    const int w = tid >> 6;          // 0..7
    const int wy = w >> 1;           // 0..3: i 64-chunk
    const int wx = w & 1;            // 0..1: j 128-chunk
    const int l31 = lane & 31;
    const int l5 = lane >> 5;
    const int f0 = w << 1;           // this wave stages frags f0, f0+1
    const int gA = i0 >> 5, gB = j0 >> 5;   // first 32-row group of each side

    f32x16 acc[2][4];
#pragma unroll
    for (int mi = 0; mi < 2; ++mi)
#pragma unroll
        for (int ni = 0; ni < 4; ++ni)
#pragma unroll
            for (int r = 0; r < 16; ++r) acc[mi][ni][r] = 0.f;

    // stage one K-64 chunk: 2 frags/wave x 2 halves, each one dense 1KB DMA
    auto stage = [&](int c, int buf) {
#pragma unroll
        for (int q = 0; q < 2; ++q) {
            int f = f0 + q;
            int grp = (f < 8) ? (gA + f) : (gB + (f - 8));
            const unsigned char* src = xb + ((size_t)((grp * 8 + c) * 2) << 10);
#pragma unroll
            for (int h = 0; h < 2; ++h)
                __builtin_amdgcn_global_load_lds(
                    (const AS1 void*)(src + (h << 10)),
                    (AS3 void*)&lds[buf][f][h << 10], 16, 0, 0);
        }
    };

    stage(0, 0);
    __syncthreads();

    for (int c = 0; c < 8; ++c) {
        const int cur = c & 1;
        if (c < 7) stage(c + 1, cur ^ 1);
        int8x af[2], bf[4];
#pragma unroll
        for (int mi = 0; mi < 2; ++mi) {
            uint4 lo = *(const uint4*)&lds[cur][wy * 2 + mi][lane << 4];
            uint4 hi = *(const uint4*)&lds[cur][wy * 2 + mi][1024 + (lane << 4)];
            af[mi][0] = lo.x; af[mi][1] = lo.y; af[mi][2] = lo.z; af[mi][3] = lo.w;
            af[mi][4] = hi.x; af[mi][5] = hi.y; af[mi][6] = hi.z; af[mi][7] = hi.w;
        }
#pragma unroll
        for (int ni = 0; ni < 4; ++ni) {
            uint4 lo = *(const uint4*)&lds[cur][8 + wx * 4 + ni][lane << 4];
            uint4 hi = *(const uint4*)&lds[cur][8 + wx * 4 + ni][1024 + (lane << 4)];
            bf[ni][0] = lo.x; bf[ni][1] = lo.y; bf[ni][2] = lo.z; bf[ni][3] = lo.w;
            bf[ni][4] = hi.x; bf[ni][5] = hi.y; bf[ni][6] = hi.z; bf[ni][7] = hi.w;
        }
#pragma unroll
        for (int mi = 0; mi < 2; ++mi)
#pragma unroll
            for (int ni = 0; ni < 4; ++ni)
                acc[mi][ni] = __builtin_amdgcn_mfma_scale_f32_32x32x64_f8f6f4(
                    af[mi], bf[ni], acc[mi][ni], 0, 0, 0, SCALE1, 0, SCALE1);
        __syncthreads();
    }

    // ---- branch-free epilogue ------------------------------------------------
    const bool offdiag = (bi != bj);
    float sqj[4];
#pragma unroll
    for (int ni = 0; ni < 4; ++ni) sqj[ni] = sq[j0 + wx * 128 + ni * 32 + l31];

    float m = NEG_INF_SENT;
#pragma unroll
    for (int mi = 0; mi < 2; ++mi) {
#pragma unroll
        for (int r = 0; r < 16; ++r) {
            int row32 = (r & 3) + 8 * (r >> 2) + 4 * l5;
            int i = i0 + wy * 64 + mi * 32 + row32;
            float sqi = sq[i];
#pragma unroll
            for (int ni = 0; ni < 4; ++ni) {
                int j = j0 + wx * 128 + ni * 32 + l31;
                float d2 = fmaxf(sqi + sqj[ni] - 2.f * acc[mi][ni][r], 0.f);
                float tv = (offdiag || j > i) ? (-2.0f * d2) : NEG_INF_SENT;
                acc[mi][ni][r] = tv;
                m = fmaxf(m, tv);
            }
        }
    }
    float s = 0.f;
#pragma unroll
    for (int mi = 0; mi < 2; ++mi)
#pragma unroll
        for (int ni = 0; ni < 4; ++ni)
#pragma unroll
            for (int r = 0; r < 16; ++r)
                s += __expf(acc[mi][ni][r] - m);

#pragma unroll
    for (int off = 32; off > 0; off >>= 1) {
        float m2 = __shfl_down(m, off, 64);
        float s2 = __shfl_down(s, off, 64);
        lse_merge(m, s, m2, s2);
    }
    __shared__ float rm[8], rs[8];
    if (lane == 0) { rm[w] = m; rs[w] = s; }
    __syncthreads();
    if (tid == 0) {
#pragma unroll
        for (int v = 1; v < 8; ++v) lse_merge(rm[0], rs[0], rm[v], rs[v]);
        bm[b] = rm[0];
        bs[b] = rs[0];
    }
}

__global__ __launch_bounds__(256) void finalize_kernel(const float* __restrict__ bm,
                                                       const float* __restrict__ bs,
                                                       int nblocks,
                                                       float* __restrict__ out) {
    const int tid = threadIdx.x;
    float m = NEG_INF_SENT, s = 0.f;
    for (int b = tid; b < nblocks; b += 256) lse_merge(m, s, bm[b], bs[b]);
#pragma unroll
    for (int off = 32; off > 0; off >>= 1) {
        float m2 = __shfl_down(m, off, 64);
        float s2 = __shfl_down(s, off, 64);
        lse_merge(m, s, m2, s2);
    }
    __shared__ float rm[4], rs[4];
    if ((tid & 63) == 0) { rm[tid >> 6] = m; rs[tid >> 6] = s; }
    __syncthreads();
    if (tid == 0) {
#pragma unroll
        for (int v = 1; v < 4; ++v) lse_merge(rm[0], rs[0], rm[v], rs[v]);
        const float log_num_pairs = 17.3285362f;  // log(8192*8191/2)
        out[0] = rm[0] + logf(rs[0]) - log_num_pairs;
    }
}

extern "C" void kernel_launch(void* const* d_in, const int* in_sizes, int n_in,
                              void* d_out, int out_size, void* d_ws, size_t ws_size,
                              hipStream_t stream) {
    const float* x = (const float*)d_in[0];
    float* out = (float*)d_out;

    const int T = N / 256;                    // 32
    const int nb = T * (T + 1) / 2;           // 528
    const size_t xb_bytes = (size_t)N * D;    // 4 MB fp8 (swizzled)

    unsigned char* xb = (unsigned char*)d_ws;
    float* sq = (float*)((char*)d_ws + xb_bytes);
    float* bm = sq + N;
    float* bs = bm + nb;

    cast_rowsq_kernel<<<N / 16, 256, 0, stream>>>(x, xb, sq);
    pair_mfma_kernel<<<nb, 512, 0, stream>>>(xb, sq, bm, bs);
    finalize_kernel<<<1, 256, 0, stream>>>(bm, bs, nb, out);
}